// Round 1
// baseline (321.646 us; speedup 1.0000x reference)
//
#include <hip/hip_runtime.h>

#define NHEADS 16
#define HDIM   64
#define SEQL   2048
#define HID    1024
#define NB     2
#define MT     4096   // NB*SEQL

typedef float        f4_t   __attribute__((ext_vector_type(4)));
typedef unsigned int u32x4  __attribute__((ext_vector_type(4)));
typedef __bf16       bf16x8 __attribute__((ext_vector_type(8)));

__device__ __forceinline__ unsigned short f2bf(float f){
  unsigned int u = __float_as_uint(f);
  unsigned int r = (u + 0x7fffu + ((u >> 16) & 1u)) >> 16;
  return (unsigned short)r;
}
__device__ __forceinline__ float bf2f(unsigned short h){
  return __uint_as_float(((unsigned int)h) << 16);
}
__device__ __forceinline__ u32x4 ld16(const unsigned short* p){
  return *reinterpret_cast<const u32x4*>(p);
}
__device__ __forceinline__ f4_t mfma_bf16(u32x4 a, u32x4 b, f4_t c){
  return __builtin_amdgcn_mfma_f32_16x16x32_bf16(
      __builtin_bit_cast(bf16x8, a), __builtin_bit_cast(bf16x8, b), c, 0, 0, 0);
}

// ---- x fp32 -> bf16 (ushort), 8 elems/thread ----
__global__ __launch_bounds__(256) void xcast(const float* __restrict__ x,
                                             unsigned short* __restrict__ xb){
  int gid = blockIdx.x * 256 + threadIdx.x;
  float4 a = reinterpret_cast<const float4*>(x)[gid * 2];
  float4 b = reinterpret_cast<const float4*>(x)[gid * 2 + 1];
  u32x4 o;
  o[0] = (unsigned)f2bf(a.x) | ((unsigned)f2bf(a.y) << 16);
  o[1] = (unsigned)f2bf(a.z) | ((unsigned)f2bf(a.w) << 16);
  o[2] = (unsigned)f2bf(b.x) | ((unsigned)f2bf(b.y) << 16);
  o[3] = (unsigned)f2bf(b.z) | ((unsigned)f2bf(b.w) << 16);
  *reinterpret_cast<u32x4*>(&xb[gid * 8]) = o;
}

// ---- W [K,N] fp32 -> W^T [N,K] bf16, 32x32 tiles ----
__global__ void prep_w(const float* __restrict__ Wq, const float* __restrict__ Wk,
                       const float* __restrict__ Wv, const float* __restrict__ Wo,
                       unsigned short* __restrict__ wqT, unsigned short* __restrict__ wkT,
                       unsigned short* __restrict__ wvT, unsigned short* __restrict__ woT){
  __shared__ float t[32][33];
  int z = blockIdx.z;
  const float* W = (z==0)?Wq:(z==1)?Wk:(z==2)?Wv:Wo;
  unsigned short* WT = (z==0)?wqT:(z==1)?wkT:(z==2)?wvT:woT;
  int k0 = blockIdx.x*32, n0 = blockIdx.y*32;
  int tx = threadIdx.x, ty = threadIdx.y;
  #pragma unroll
  for (int ii=0; ii<4; ii++)
    t[ty+ii*8][tx] = W[(k0+ty+ii*8)*HID + n0+tx];
  __syncthreads();
  #pragma unroll
  for (int ii=0; ii<4; ii++)
    WT[(n0+ty+ii*8)*HID + k0+tx] = f2bf(t[tx][ty+ii*8]);
}

// ---- QKV GEMM: C = xb[4096,1024] * WT[n,k]^T + bias, write [b,h,s,d] bf16 ----
__global__ __launch_bounds__(256) void qkv_gemm(
    const unsigned short* __restrict__ xb,
    const unsigned short* __restrict__ wqT, const unsigned short* __restrict__ wkT,
    const unsigned short* __restrict__ wvT,
    const float* __restrict__ bq, const float* __restrict__ bk, const float* __restrict__ bv,
    unsigned short* __restrict__ qo, unsigned short* __restrict__ ko,
    unsigned short* __restrict__ vo){
  __shared__ unsigned short As[128*32];
  __shared__ unsigned short Bs[128*32];
  const int z = blockIdx.z;
  const unsigned short* wT = (z==0)?wqT:(z==1)?wkT:wvT;
  const float* bias = (z==0)?bq:(z==1)?bk:bv;
  unsigned short* outp = (z==0)?qo:(z==1)?ko:vo;
  const int m0 = blockIdx.x * 128;
  const int n0 = blockIdx.y * 128;
  const int tid = threadIdx.x;
  const int lane = tid & 63, w = tid >> 6;
  const int l15 = lane & 15, lg = lane >> 4;
  const int wr = (w >> 1) * 64, wc = (w & 1) * 64;

  f4_t acc[4][4];
  f4_t z4 = {0.f, 0.f, 0.f, 0.f};
  #pragma unroll
  for (int i=0;i<4;i++)
    #pragma unroll
    for (int j=0;j<4;j++) acc[i][j] = z4;

  for (int kt = 0; kt < HID; kt += 32) {
    __syncthreads();
    #pragma unroll
    for (int c = 0; c < 2; c++) {
      int lin = c*256 + tid;
      int row = lin >> 2;
      int kc = (lin & 3) * 8;
      *reinterpret_cast<u32x4*>(&As[lin*8]) =
          *reinterpret_cast<const u32x4*>(&xb[(m0+row)*HID + kt + kc]);
      *reinterpret_cast<u32x4*>(&Bs[lin*8]) =
          *reinterpret_cast<const u32x4*>(&wT[(n0+row)*HID + kt + kc]);
    }
    __syncthreads();
    u32x4 a[4], b[4];
    #pragma unroll
    for (int i=0;i<4;i++) a[i] = ld16(&As[(wr + i*16 + l15)*32 + lg*8]);
    #pragma unroll
    for (int j=0;j<4;j++) b[j] = ld16(&Bs[(wc + j*16 + l15)*32 + lg*8]);
    #pragma unroll
    for (int i=0;i<4;i++)
      #pragma unroll
      for (int j=0;j<4;j++)
        acc[i][j] = mfma_bf16(a[i], b[j], acc[i][j]);
  }
  #pragma unroll
  for (int i=0;i<4;i++){
    int mrow = m0 + wr + i*16 + lg*4;
    #pragma unroll
    for (int j=0;j<4;j++){
      int n = n0 + wc + j*16 + l15;
      float bs = bias[n];
      int h = n >> 6, d = n & 63;
      #pragma unroll
      for (int r=0;r<4;r++){
        int m = mrow + r;
        int b_ = m >> 11, s = m & 2047;
        outp[(((b_*NHEADS + h)*SEQL) + s)*HDIM + d] = f2bf(acc[i][j][r] + bs);
      }
    }
  }
}

// ---- v [bh,s,d] -> vT [bh,d,s] ----
__global__ void vtrans(const unsigned short* __restrict__ v,
                       unsigned short* __restrict__ vT){
  __shared__ unsigned short t[32][33];
  int bh = blockIdx.z;
  int s0 = blockIdx.x*32, d0 = blockIdx.y*32;
  int tx = threadIdx.x, ty = threadIdx.y;
  const unsigned short* vbp = v + bh*SEQL*HDIM;
  unsigned short* vTp = vT + bh*HDIM*SEQL;
  #pragma unroll
  for (int ii=0; ii<4; ii++)
    t[ty+ii*8][tx] = vbp[(s0+ty+ii*8)*HDIM + d0+tx];
  __syncthreads();
  #pragma unroll
  for (int ii=0; ii<4; ii++)
    vTp[(d0+ty+ii*8)*SEQL + s0+tx] = t[tx][ty+ii*8];
}

// ---- flash attention: 4 waves/block, 16 q-rows/wave, 64-key blocks ----
__global__ __launch_bounds__(256) void flash(
    const unsigned short* __restrict__ q,   // [bh][s][d]
    const unsigned short* __restrict__ k,   // [bh][s][d]
    const unsigned short* __restrict__ vT,  // [bh][d][s]
    unsigned short* __restrict__ ctx){      // [b][s][HID] bf16
  __shared__ unsigned short plds[4][16*64];
  const int bh = blockIdx.y;
  const int b_ = bh >> 4, h = bh & 15;
  const int tid = threadIdx.x;
  const int w = tid >> 6, lane = tid & 63;
  const int l15 = lane & 15, lg = lane >> 4;
  const int q0 = blockIdx.x*64 + w*16;
  const unsigned short* qb = q + (bh*SEQL + q0)*HDIM;
  const unsigned short* kp = k + bh*SEQL*HDIM;
  const unsigned short* vp = vT + bh*HDIM*SEQL;
  unsigned short* pw = plds[w];

  u32x4 aq0 = ld16(&qb[l15*HDIM + lg*8]);
  u32x4 aq1 = ld16(&qb[l15*HDIM + 32 + lg*8]);

  float mr[4], ls[4];
  f4_t oacc[4];
  f4_t z4 = {0.f,0.f,0.f,0.f};
  #pragma unroll
  for (int r=0;r<4;r++){ mr[r] = -1e30f; ls[r] = 0.f; }
  #pragma unroll
  for (int dt=0;dt<4;dt++) oacc[dt] = z4;

  for (int kb0 = 0; kb0 < SEQL; kb0 += 64) {
    f4_t sacc[4];
    #pragma unroll
    for (int t=0;t<4;t++){
      u32x4 k0f = ld16(&kp[(kb0 + t*16 + l15)*HDIM + lg*8]);
      u32x4 k1f = ld16(&kp[(kb0 + t*16 + l15)*HDIM + 32 + lg*8]);
      f4_t s = mfma_bf16(aq0, k0f, z4);
      s = mfma_bf16(aq1, k1f, s);
      sacc[t] = s * 0.125f;   // 1/sqrt(64)
    }
    float mnew[4], scl[4];
    #pragma unroll
    for (int r=0;r<4;r++){
      float vm = fmaxf(fmaxf(sacc[0][r], sacc[1][r]), fmaxf(sacc[2][r], sacc[3][r]));
      #pragma unroll
      for (int sft=1; sft<16; sft<<=1) vm = fmaxf(vm, __shfl_xor(vm, sft));
      mnew[r] = fmaxf(mr[r], vm);
      scl[r] = __expf(mr[r] - mnew[r]);
      mr[r] = mnew[r];
    }
    #pragma unroll
    for (int r=0;r<4;r++){
      float ps = 0.f;
      #pragma unroll
      for (int t=0;t<4;t++){
        float p = __expf(sacc[t][r] - mnew[r]);
        pw[(lg*4 + r)*64 + t*16 + l15] = f2bf(p);
        ps += p;
      }
      #pragma unroll
      for (int sft=1; sft<16; sft<<=1) ps += __shfl_xor(ps, sft);
      ls[r] = ls[r]*scl[r] + ps;
    }
    #pragma unroll
    for (int dt=0;dt<4;dt++)
      #pragma unroll
      for (int r=0;r<4;r++) oacc[dt][r] = oacc[dt][r] * scl[r];

    u32x4 pa0 = ld16(&pw[l15*64 + lg*8]);
    u32x4 pa1 = ld16(&pw[l15*64 + 32 + lg*8]);
    #pragma unroll
    for (int dt=0;dt<4;dt++){
      u32x4 v0 = ld16(&vp[(dt*16 + l15)*SEQL + kb0 + lg*8]);
      u32x4 v1 = ld16(&vp[(dt*16 + l15)*SEQL + kb0 + 32 + lg*8]);
      f4_t o = mfma_bf16(pa0, v0, oacc[dt]);
      oacc[dt] = mfma_bf16(pa1, v1, o);
    }
  }
  #pragma unroll
  for (int dt=0;dt<4;dt++){
    #pragma unroll
    for (int r=0;r<4;r++){
      float val = oacc[dt][r] / ls[r];
      ctx[(b_*SEQL + q0 + lg*4 + r)*HID + h*HDIM + dt*16 + l15] = f2bf(val);
    }
  }
}

// ---- out GEMM: out = ctx[4096,1024] * woT[n,k]^T + bo (fp32 out) ----
__global__ __launch_bounds__(256) void out_gemm(
    const unsigned short* __restrict__ cb,
    const unsigned short* __restrict__ woT,
    const float* __restrict__ bo,
    float* __restrict__ out){
  __shared__ unsigned short As[128*32];
  __shared__ unsigned short Bs[128*32];
  const int m0 = blockIdx.x * 128;
  const int n0 = blockIdx.y * 128;
  const int tid = threadIdx.x;
  const int lane = tid & 63, w = tid >> 6;
  const int l15 = lane & 15, lg = lane >> 4;
  const int wr = (w >> 1) * 64, wc = (w & 1) * 64;

  f4_t acc[4][4];
  f4_t z4 = {0.f,0.f,0.f,0.f};
  #pragma unroll
  for (int i=0;i<4;i++)
    #pragma unroll
    for (int j=0;j<4;j++) acc[i][j] = z4;

  for (int kt = 0; kt < HID; kt += 32) {
    __syncthreads();
    #pragma unroll
    for (int c = 0; c < 2; c++) {
      int lin = c*256 + tid;
      int row = lin >> 2;
      int kc = (lin & 3) * 8;
      *reinterpret_cast<u32x4*>(&As[lin*8]) =
          *reinterpret_cast<const u32x4*>(&cb[(m0+row)*HID + kt + kc]);
      *reinterpret_cast<u32x4*>(&Bs[lin*8]) =
          *reinterpret_cast<const u32x4*>(&woT[(n0+row)*HID + kt + kc]);
    }
    __syncthreads();
    u32x4 a[4], b[4];
    #pragma unroll
    for (int i=0;i<4;i++) a[i] = ld16(&As[(wr + i*16 + l15)*32 + lg*8]);
    #pragma unroll
    for (int j=0;j<4;j++) b[j] = ld16(&Bs[(wc + j*16 + l15)*32 + lg*8]);
    #pragma unroll
    for (int i=0;i<4;i++)
      #pragma unroll
      for (int j=0;j<4;j++)
        acc[i][j] = mfma_bf16(a[i], b[j], acc[i][j]);
  }
  #pragma unroll
  for (int i=0;i<4;i++){
    int mrow = m0 + wr + i*16 + lg*4;
    #pragma unroll
    for (int j=0;j<4;j++){
      int n = n0 + wc + j*16 + l15;
      float bs = bo[n];
      #pragma unroll
      for (int r=0;r<4;r++)
        out[(mrow + r)*HID + n] = acc[i][j][r] + bs;
    }
  }
}

extern "C" void kernel_launch(void* const* d_in, const int* in_sizes, int n_in,
                              void* d_out, int out_size, void* d_ws, size_t ws_size,
                              hipStream_t stream){
  const float* x  = (const float*)d_in[0];
  const float* Wq = (const float*)d_in[1];
  const float* bq = (const float*)d_in[2];
  const float* Wk = (const float*)d_in[3];
  const float* bk = (const float*)d_in[4];
  const float* Wv = (const float*)d_in[5];
  const float* bv = (const float*)d_in[6];
  const float* Wo = (const float*)d_in[7];
  const float* bo = (const float*)d_in[8];
  float* out = (float*)d_out;

  char* ws = (char*)d_ws;
  size_t off = 0;
  auto alloc = [&](size_t bytes) -> void* {
    void* p = ws + off;
    off += (bytes + 255) & ~(size_t)255;
    return p;
  };
  unsigned short* xb   = (unsigned short*)alloc((size_t)MT*HID*2);
  unsigned short* wqT  = (unsigned short*)alloc((size_t)HID*HID*2);
  unsigned short* wkT  = (unsigned short*)alloc((size_t)HID*HID*2);
  unsigned short* wvT  = (unsigned short*)alloc((size_t)HID*HID*2);
  unsigned short* woT  = (unsigned short*)alloc((size_t)HID*HID*2);
  unsigned short* q_ws = (unsigned short*)alloc((size_t)MT*HID*2);
  unsigned short* k_ws = (unsigned short*)alloc((size_t)MT*HID*2);
  unsigned short* v_ws = (unsigned short*)alloc((size_t)MT*HID*2);
  unsigned short* vT_ws= (unsigned short*)alloc((size_t)MT*HID*2);
  unsigned short* c_ws = (unsigned short*)alloc((size_t)MT*HID*2);

  prep_w<<<dim3(32,32,4), dim3(32,8), 0, stream>>>(Wq,Wk,Wv,Wo, wqT,wkT,wvT,woT);
  xcast<<<dim3(2048), dim3(256), 0, stream>>>(x, xb);
  qkv_gemm<<<dim3(32,8,3), dim3(256), 0, stream>>>(xb, wqT,wkT,wvT, bq,bk,bv,
                                                   q_ws, k_ws, v_ws);
  vtrans<<<dim3(64,2,32), dim3(32,8), 0, stream>>>(v_ws, vT_ws);
  flash<<<dim3(32,32), dim3(256), 0, stream>>>(q_ws, k_ws, vT_ws, c_ws);
  out_gemm<<<dim3(32,8), dim3(256), 0, stream>>>(c_ws, woT, bo, out);
}

// Round 2
// 315.548 us; speedup vs baseline: 1.0193x; 1.0193x over previous
//
#include <hip/hip_runtime.h>

#define NHEADS 16
#define HDIM   64
#define SEQL   2048
#define HID    1024
#define NB     2
#define MT     4096   // NB*SEQL

// softmax scale folded into Wq/bq: 1/sqrt(64) * log2(e)
#define QSCALE 0.18033688011112042f

typedef float        f4_t   __attribute__((ext_vector_type(4)));
typedef unsigned int u32x4  __attribute__((ext_vector_type(4)));
typedef __bf16       bf16x8 __attribute__((ext_vector_type(8)));

__device__ __forceinline__ unsigned int pkbf(float a, float b){
  unsigned short lo = __builtin_bit_cast(unsigned short, (__bf16)a);
  unsigned short hi = __builtin_bit_cast(unsigned short, (__bf16)b);
  return (unsigned)lo | ((unsigned)hi << 16);
}
__device__ __forceinline__ unsigned short f2bf(float f){
  return __builtin_bit_cast(unsigned short, (__bf16)f);
}
__device__ __forceinline__ u32x4 ld16(const unsigned short* p){
  return *reinterpret_cast<const u32x4*>(p);
}
__device__ __forceinline__ f4_t mfma_bf16(u32x4 a, u32x4 b, f4_t c){
  return __builtin_amdgcn_mfma_f32_16x16x32_bf16(
      __builtin_bit_cast(bf16x8, a), __builtin_bit_cast(bf16x8, b), c, 0, 0, 0);
}

// ---- x fp32 -> bf16 (ushort), 8 elems/thread ----
__global__ __launch_bounds__(256) void xcast(const float* __restrict__ x,
                                             unsigned short* __restrict__ xb){
  int gid = blockIdx.x * 256 + threadIdx.x;
  float4 a = reinterpret_cast<const float4*>(x)[gid * 2];
  float4 b = reinterpret_cast<const float4*>(x)[gid * 2 + 1];
  u32x4 o;
  o[0] = pkbf(a.x, a.y);
  o[1] = pkbf(a.z, a.w);
  o[2] = pkbf(b.x, b.y);
  o[3] = pkbf(b.z, b.w);
  *reinterpret_cast<u32x4*>(&xb[gid * 8]) = o;
}

// ---- W [K,N] fp32 -> W^T [N,K] bf16, 32x32 tiles; Wq scaled by QSCALE ----
__global__ void prep_w(const float* __restrict__ Wq, const float* __restrict__ Wk,
                       const float* __restrict__ Wv, const float* __restrict__ Wo,
                       unsigned short* __restrict__ wqT, unsigned short* __restrict__ wkT,
                       unsigned short* __restrict__ wvT, unsigned short* __restrict__ woT){
  __shared__ float t[32][33];
  int z = blockIdx.z;
  const float* W = (z==0)?Wq:(z==1)?Wk:(z==2)?Wv:Wo;
  unsigned short* WT = (z==0)?wqT:(z==1)?wkT:(z==2)?wvT:woT;
  float sc = (z==0) ? QSCALE : 1.0f;
  int k0 = blockIdx.x*32, n0 = blockIdx.y*32;
  int tx = threadIdx.x, ty = threadIdx.y;
  #pragma unroll
  for (int ii=0; ii<4; ii++)
    t[ty+ii*8][tx] = W[(k0+ty+ii*8)*HID + n0+tx];
  __syncthreads();
  #pragma unroll
  for (int ii=0; ii<4; ii++)
    WT[(n0+ty+ii*8)*HID + k0+tx] = f2bf(t[tx][ty+ii*8] * sc);
}

// ---- QKV GEMM: C = xb[4096,1024] * WT[n,k]^T + bias ----
// z==0 -> q [bh,s,d] (pre-scaled), z==1 -> k [bh,s,d], z==2 -> vT [bh,d,s]
__global__ __launch_bounds__(256) void qkv_gemm(
    const unsigned short* __restrict__ xb,
    const unsigned short* __restrict__ wqT, const unsigned short* __restrict__ wkT,
    const unsigned short* __restrict__ wvT,
    const float* __restrict__ bq, const float* __restrict__ bk, const float* __restrict__ bv,
    unsigned short* __restrict__ qo, unsigned short* __restrict__ ko,
    unsigned short* __restrict__ vto){
  __shared__ unsigned short As[128*32];
  __shared__ unsigned short Bs[128*32];
  const int z = blockIdx.z;
  const unsigned short* wT = (z==0)?wqT:(z==1)?wkT:wvT;
  const float* bias = (z==0)?bq:(z==1)?bk:bv;
  const float bscale = (z==0) ? QSCALE : 1.0f;
  const int m0 = blockIdx.x * 128;
  const int n0 = blockIdx.y * 128;
  const int tid = threadIdx.x;
  const int lane = tid & 63, w = tid >> 6;
  const int l15 = lane & 15, lg = lane >> 4;
  const int wr = (w >> 1) * 64, wc = (w & 1) * 64;

  f4_t acc[4][4];
  f4_t z4 = {0.f, 0.f, 0.f, 0.f};
  #pragma unroll
  for (int i=0;i<4;i++)
    #pragma unroll
    for (int j=0;j<4;j++) acc[i][j] = z4;

  for (int kt = 0; kt < HID; kt += 32) {
    __syncthreads();
    #pragma unroll
    for (int c = 0; c < 2; c++) {
      int lin = c*256 + tid;
      int row = lin >> 2;
      int kc = (lin & 3) * 8;
      *reinterpret_cast<u32x4*>(&As[lin*8]) =
          *reinterpret_cast<const u32x4*>(&xb[(m0+row)*HID + kt + kc]);
      *reinterpret_cast<u32x4*>(&Bs[lin*8]) =
          *reinterpret_cast<const u32x4*>(&wT[(n0+row)*HID + kt + kc]);
    }
    __syncthreads();
    u32x4 a[4], b[4];
    #pragma unroll
    for (int i=0;i<4;i++) a[i] = ld16(&As[(wr + i*16 + l15)*32 + lg*8]);
    #pragma unroll
    for (int j=0;j<4;j++) b[j] = ld16(&Bs[(wc + j*16 + l15)*32 + lg*8]);
    #pragma unroll
    for (int i=0;i<4;i++)
      #pragma unroll
      for (int j=0;j<4;j++)
        acc[i][j] = mfma_bf16(a[i], b[j], acc[i][j]);
  }
  if (z == 2) {
    // write vT [bh][d][s], 4 consecutive s packed per 8B store
    #pragma unroll
    for (int i=0;i<4;i++){
      int mrow = m0 + wr + i*16 + lg*4;
      int b_ = mrow >> 11, s = mrow & 2047;
      #pragma unroll
      for (int j=0;j<4;j++){
        int n = n0 + wc + j*16 + l15;
        float bs = bias[n];
        int h = n >> 6, d = n & 63;
        unsigned int lo = pkbf(acc[i][j][0]+bs, acc[i][j][1]+bs);
        unsigned int hi = pkbf(acc[i][j][2]+bs, acc[i][j][3]+bs);
        unsigned long long v8 = (unsigned long long)lo | ((unsigned long long)hi << 32);
        *reinterpret_cast<unsigned long long*>(
            vto + (((b_*NHEADS + h)*HDIM + d)*SEQL + s)) = v8;
      }
    }
  } else {
    unsigned short* outp = (z==0) ? qo : ko;
    #pragma unroll
    for (int i=0;i<4;i++){
      int mrow = m0 + wr + i*16 + lg*4;
      #pragma unroll
      for (int j=0;j<4;j++){
        int n = n0 + wc + j*16 + l15;
        float bs = bias[n] * bscale;
        int h = n >> 6, d = n & 63;
        #pragma unroll
        for (int r=0;r<4;r++){
          int m = mrow + r;
          int b_ = m >> 11, s = m & 2047;
          outp[(((b_*NHEADS + h)*SEQL) + s)*HDIM + d] = f2bf(acc[i][j][r] + bs);
        }
      }
    }
  }
}

// ---- flash attention, swapped-operand form ----
// S^T = mfma(K, Q): lane holds 16 scores of its own q-row (q = lane&15).
// O^T = mfma(vT, P): rescale factor lane-uniform. P relayout via swizzled LDS.
__global__ __launch_bounds__(256) void flash(
    const unsigned short* __restrict__ q,   // [bh][s][d], pre-scaled by QSCALE
    const unsigned short* __restrict__ k,   // [bh][s][d]
    const unsigned short* __restrict__ vT,  // [bh][d][s]
    unsigned short* __restrict__ ctx){      // [b][s][HID] bf16
  __shared__ unsigned short plds[4][16*64]; // 2KB per wave
  const int bh = blockIdx.y;
  const int b_ = bh >> 4, h = bh & 15;
  const int tid = threadIdx.x;
  const int w = tid >> 6, lane = tid & 63;
  const int l15 = lane & 15, lg = lane >> 4;
  const int q0 = blockIdx.x*64 + w*16;
  const unsigned short* qb = q + (bh*SEQL + q0)*HDIM;
  const unsigned short* kp = k + bh*SEQL*HDIM;
  const unsigned short* vp = vT + bh*HDIM*SEQL;
  char* pwb = (char*)plds[w];
  const int swz   = (l15 & 7) << 4;          // XOR swizzle, bits 4-6
  const int wbase = l15*128 + lg*8;          // write base (logical bytes)
  const int rbase = l15*128 + lg*16;         // read base  (logical bytes)

  u32x4 aq0 = ld16(&qb[l15*HDIM + lg*8]);
  u32x4 aq1 = ld16(&qb[l15*HDIM + 32 + lg*8]);

  float mr = -1e30f, ls = 0.f;
  f4_t oacc[4];
  f4_t z4 = {0.f,0.f,0.f,0.f};
  #pragma unroll
  for (int dt=0;dt<4;dt++) oacc[dt] = z4;

  for (int kb0 = 0; kb0 < SEQL; kb0 += 64) {
    f4_t sc[4];
    #pragma unroll
    for (int t=0;t<4;t++){
      u32x4 k0f = ld16(&kp[(kb0 + t*16 + l15)*HDIM + lg*8]);
      u32x4 k1f = ld16(&kp[(kb0 + t*16 + l15)*HDIM + 32 + lg*8]);
      f4_t s = mfma_bf16(k0f, aq0, z4);
      sc[t] = mfma_bf16(k1f, aq1, s);
    }
    // row max: 15 in-register + 2 shuffles (scores already in log2 domain)
    float vm = sc[0][0];
    #pragma unroll
    for (int t=0;t<4;t++)
      #pragma unroll
      for (int r=0;r<4;r++) vm = fmaxf(vm, sc[t][r]);
    vm = fmaxf(vm, __shfl_xor(vm, 16));
    vm = fmaxf(vm, __shfl_xor(vm, 32));
    float mnew = fmaxf(mr, vm);
    float scl = exp2f(mr - mnew);
    mr = mnew;
    float ps = 0.f;
    #pragma unroll
    for (int t=0;t<4;t++)
      #pragma unroll
      for (int r=0;r<4;r++){
        float p = exp2f(sc[t][r] - mnew);
        sc[t][r] = p;
        ps += p;
      }
    ps += __shfl_xor(ps, 16);
    ps += __shfl_xor(ps, 32);
    ls = ls*scl + ps;
    // pack P (bf16) into swizzled LDS: 4x ds_write_b64
    #pragma unroll
    for (int t=0;t<4;t++){
      unsigned int lo = pkbf(sc[t][0], sc[t][1]);
      unsigned int hi = pkbf(sc[t][2], sc[t][3]);
      unsigned long long v8 = (unsigned long long)lo | ((unsigned long long)hi << 32);
      *reinterpret_cast<unsigned long long*>(pwb + ((wbase + 32*t) ^ swz)) = v8;
    }
    #pragma unroll
    for (int dt=0;dt<4;dt++) oacc[dt] *= scl;
    // read P as B-fragments: 2x ds_read_b128 (same-wave data, in-order LDS)
    u32x4 p0 = *reinterpret_cast<const u32x4*>(pwb + (rbase ^ swz));
    u32x4 p1 = *reinterpret_cast<const u32x4*>(pwb + ((rbase + 64) ^ swz));
    #pragma unroll
    for (int dt=0;dt<4;dt++){
      u32x4 v0 = ld16(&vp[(dt*16 + l15)*SEQL + kb0 + lg*8]);
      u32x4 v1 = ld16(&vp[(dt*16 + l15)*SEQL + kb0 + 32 + lg*8]);
      f4_t o = mfma_bf16(v0, p0, oacc[dt]);
      oacc[dt] = mfma_bf16(v1, p1, o);
    }
  }
  float inv = 1.0f / ls;
  int orow = b_*SEQL + q0 + l15;
  unsigned short* cb = ctx + orow*HID + h*HDIM;
  #pragma unroll
  for (int dt=0;dt<4;dt++){
    unsigned int lo = pkbf(oacc[dt][0]*inv, oacc[dt][1]*inv);
    unsigned int hi = pkbf(oacc[dt][2]*inv, oacc[dt][3]*inv);
    unsigned long long v8 = (unsigned long long)lo | ((unsigned long long)hi << 32);
    *reinterpret_cast<unsigned long long*>(cb + dt*16 + lg*4) = v8;
  }
}

// ---- out GEMM: out = ctx[4096,1024] * woT[n,k]^T + bo (fp32 out) ----
__global__ __launch_bounds__(256) void out_gemm(
    const unsigned short* __restrict__ cb,
    const unsigned short* __restrict__ woT,
    const float* __restrict__ bo,
    float* __restrict__ out){
  __shared__ unsigned short As[128*32];
  __shared__ unsigned short Bs[128*32];
  const int m0 = blockIdx.x * 128;
  const int n0 = blockIdx.y * 128;
  const int tid = threadIdx.x;
  const int lane = tid & 63, w = tid >> 6;
  const int l15 = lane & 15, lg = lane >> 4;
  const int wr = (w >> 1) * 64, wc = (w & 1) * 64;

  f4_t acc[4][4];
  f4_t z4 = {0.f,0.f,0.f,0.f};
  #pragma unroll
  for (int i=0;i<4;i++)
    #pragma unroll
    for (int j=0;j<4;j++) acc[i][j] = z4;

  for (int kt = 0; kt < HID; kt += 32) {
    __syncthreads();
    #pragma unroll
    for (int c = 0; c < 2; c++) {
      int lin = c*256 + tid;
      int row = lin >> 2;
      int kc = (lin & 3) * 8;
      *reinterpret_cast<u32x4*>(&As[lin*8]) =
          *reinterpret_cast<const u32x4*>(&cb[(m0+row)*HID + kt + kc]);
      *reinterpret_cast<u32x4*>(&Bs[lin*8]) =
          *reinterpret_cast<const u32x4*>(&woT[(n0+row)*HID + kt + kc]);
    }
    __syncthreads();
    u32x4 a[4], b[4];
    #pragma unroll
    for (int i=0;i<4;i++) a[i] = ld16(&As[(wr + i*16 + l15)*32 + lg*8]);
    #pragma unroll
    for (int j=0;j<4;j++) b[j] = ld16(&Bs[(wc + j*16 + l15)*32 + lg*8]);
    #pragma unroll
    for (int i=0;i<4;i++)
      #pragma unroll
      for (int j=0;j<4;j++)
        acc[i][j] = mfma_bf16(a[i], b[j], acc[i][j]);
  }
  #pragma unroll
  for (int i=0;i<4;i++){
    int mrow = m0 + wr + i*16 + lg*4;
    #pragma unroll
    for (int j=0;j<4;j++){
      int n = n0 + wc + j*16 + l15;
      float bs = bo[n];
      #pragma unroll
      for (int r=0;r<4;r++)
        out[(mrow + r)*HID + n] = acc[i][j][r] + bs;
    }
  }
}

extern "C" void kernel_launch(void* const* d_in, const int* in_sizes, int n_in,
                              void* d_out, int out_size, void* d_ws, size_t ws_size,
                              hipStream_t stream){
  const float* x  = (const float*)d_in[0];
  const float* Wq = (const float*)d_in[1];
  const float* bq = (const float*)d_in[2];
  const float* Wk = (const float*)d_in[3];
  const float* bk = (const float*)d_in[4];
  const float* Wv = (const float*)d_in[5];
  const float* bv = (const float*)d_in[6];
  const float* Wo = (const float*)d_in[7];
  const float* bo = (const float*)d_in[8];
  float* out = (float*)d_out;

  char* ws = (char*)d_ws;
  size_t off = 0;
  auto alloc = [&](size_t bytes) -> void* {
    void* p = ws + off;
    off += (bytes + 255) & ~(size_t)255;
    return p;
  };
  unsigned short* xb   = (unsigned short*)alloc((size_t)MT*HID*2);
  unsigned short* wqT  = (unsigned short*)alloc((size_t)HID*HID*2);
  unsigned short* wkT  = (unsigned short*)alloc((size_t)HID*HID*2);
  unsigned short* wvT  = (unsigned short*)alloc((size_t)HID*HID*2);
  unsigned short* woT  = (unsigned short*)alloc((size_t)HID*HID*2);
  unsigned short* q_ws = (unsigned short*)alloc((size_t)MT*HID*2);
  unsigned short* k_ws = (unsigned short*)alloc((size_t)MT*HID*2);
  unsigned short* vT_ws= (unsigned short*)alloc((size_t)MT*HID*2);
  unsigned short* c_ws = (unsigned short*)alloc((size_t)MT*HID*2);

  prep_w<<<dim3(32,32,4), dim3(32,8), 0, stream>>>(Wq,Wk,Wv,Wo, wqT,wkT,wvT,woT);
  xcast<<<dim3(2048), dim3(256), 0, stream>>>(x, xb);
  qkv_gemm<<<dim3(32,8,3), dim3(256), 0, stream>>>(xb, wqT,wkT,wvT, bq,bk,bv,
                                                   q_ws, k_ws, vT_ws);
  flash<<<dim3(32,32), dim3(256), 0, stream>>>(q_ws, k_ws, vT_ws, c_ws);
  out_gemm<<<dim3(32,8), dim3(256), 0, stream>>>(c_ws, woT, bo, out);
}

// Round 3
// 177.840 us; speedup vs baseline: 1.8086x; 1.7743x over previous
//
#include <hip/hip_runtime.h>

#define NHEADS 16
#define HDIM   64
#define SEQL   2048
#define HID    1024
#define NB     2
#define MT     4096   // NB*SEQL

// softmax scale folded into Wq/bq: 1/sqrt(64) * log2(e)
#define QSCALE 0.18033688011112042f

typedef float        f4_t   __attribute__((ext_vector_type(4)));
typedef unsigned int u32x4  __attribute__((ext_vector_type(4)));
typedef __bf16       bf16x8 __attribute__((ext_vector_type(8)));

typedef const __attribute__((address_space(1))) unsigned int* gas_ptr;
typedef __attribute__((address_space(3))) unsigned int*       las_ptr;

__device__ __forceinline__ void gload16(const void* g, void* l){
  // dest is wave-uniform base; HW writes lane i at base + i*16
  __builtin_amdgcn_global_load_lds((gas_ptr)g, (las_ptr)l, 16, 0, 0);
}
__device__ __forceinline__ unsigned int pkbf(float a, float b){
  unsigned short lo = __builtin_bit_cast(unsigned short, (__bf16)a);
  unsigned short hi = __builtin_bit_cast(unsigned short, (__bf16)b);
  return (unsigned)lo | ((unsigned)hi << 16);
}
__device__ __forceinline__ unsigned short f2bf(float f){
  return __builtin_bit_cast(unsigned short, (__bf16)f);
}
__device__ __forceinline__ u32x4 ld16(const unsigned short* p){
  return *reinterpret_cast<const u32x4*>(p);
}
__device__ __forceinline__ f4_t mfma_bf16(u32x4 a, u32x4 b, f4_t c){
  return __builtin_amdgcn_mfma_f32_16x16x32_bf16(
      __builtin_bit_cast(bf16x8, a), __builtin_bit_cast(bf16x8, b), c, 0, 0, 0);
}

// ---- x fp32 -> bf16 (ushort), 8 elems/thread ----
__global__ __launch_bounds__(256) void xcast(const float* __restrict__ x,
                                             unsigned short* __restrict__ xb){
  int gid = blockIdx.x * 256 + threadIdx.x;
  float4 a = reinterpret_cast<const float4*>(x)[gid * 2];
  float4 b = reinterpret_cast<const float4*>(x)[gid * 2 + 1];
  u32x4 o;
  o[0] = pkbf(a.x, a.y);
  o[1] = pkbf(a.z, a.w);
  o[2] = pkbf(b.x, b.y);
  o[3] = pkbf(b.z, b.w);
  *reinterpret_cast<u32x4*>(&xb[gid * 8]) = o;
}

// ---- W [K,N] fp32 -> W^T [N,K] bf16, 32x32 tiles; Wq scaled by QSCALE ----
__global__ void prep_w(const float* __restrict__ Wq, const float* __restrict__ Wk,
                       const float* __restrict__ Wv, const float* __restrict__ Wo,
                       unsigned short* __restrict__ wqT, unsigned short* __restrict__ wkT,
                       unsigned short* __restrict__ wvT, unsigned short* __restrict__ woT){
  __shared__ float t[32][33];
  int z = blockIdx.z;
  const float* W = (z==0)?Wq:(z==1)?Wk:(z==2)?Wv:Wo;
  unsigned short* WT = (z==0)?wqT:(z==1)?wkT:(z==2)?wvT:woT;
  float sc = (z==0) ? QSCALE : 1.0f;
  int k0 = blockIdx.x*32, n0 = blockIdx.y*32;
  int tx = threadIdx.x, ty = threadIdx.y;
  #pragma unroll
  for (int ii=0; ii<4; ii++)
    t[ty+ii*8][tx] = W[(k0+ty+ii*8)*HID + n0+tx];
  __syncthreads();
  #pragma unroll
  for (int ii=0; ii<4; ii++)
    WT[(n0+ty+ii*8)*HID + k0+tx] = f2bf(t[tx][ty+ii*8] * sc);
}

// ---- QKV GEMM: C = xb[4096,1024] * WT[n,k]^T + bias ----
// z==0 -> q [bh,s,d] (pre-scaled), z==1 -> k [bh,s,d], z==2 -> vT [bh,d,s]
__global__ __launch_bounds__(256) void qkv_gemm(
    const unsigned short* __restrict__ xb,
    const unsigned short* __restrict__ wqT, const unsigned short* __restrict__ wkT,
    const unsigned short* __restrict__ wvT,
    const float* __restrict__ bq, const float* __restrict__ bk, const float* __restrict__ bv,
    unsigned short* __restrict__ qo, unsigned short* __restrict__ ko,
    unsigned short* __restrict__ vto){
  __shared__ unsigned short As[128*32];
  __shared__ unsigned short Bs[128*32];
  const int z = blockIdx.z;
  const unsigned short* wT = (z==0)?wqT:(z==1)?wkT:wvT;
  const float* bias = (z==0)?bq:(z==1)?bk:bv;
  const float bscale = (z==0) ? QSCALE : 1.0f;
  const int m0 = blockIdx.x * 128;
  const int n0 = blockIdx.y * 128;
  const int tid = threadIdx.x;
  const int lane = tid & 63, w = tid >> 6;
  const int l15 = lane & 15, lg = lane >> 4;
  const int wr = (w >> 1) * 64, wc = (w & 1) * 64;
  const int srow = w*16 + (lane >> 2);     // staging row within 64-row chunk
  const int skc  = (lane & 3) * 8;         // staging k-chunk

  f4_t acc[4][4];
  f4_t z4 = {0.f, 0.f, 0.f, 0.f};
  #pragma unroll
  for (int i=0;i<4;i++)
    #pragma unroll
    for (int j=0;j<4;j++) acc[i][j] = z4;

  for (int kt = 0; kt < HID; kt += 32) {
    __syncthreads();
    #pragma unroll
    for (int c = 0; c < 2; c++) {
      int row = c*64 + srow;
      gload16(&xb[(m0+row)*HID + kt + skc], (char*)As + c*4096 + w*1024);
      gload16(&wT[(n0+row)*HID + kt + skc], (char*)Bs + c*4096 + w*1024);
    }
    __syncthreads();
    u32x4 a[4], b[4];
    #pragma unroll
    for (int i=0;i<4;i++) a[i] = ld16(&As[(wr + i*16 + l15)*32 + lg*8]);
    #pragma unroll
    for (int j=0;j<4;j++) b[j] = ld16(&Bs[(wc + j*16 + l15)*32 + lg*8]);
    #pragma unroll
    for (int i=0;i<4;i++)
      #pragma unroll
      for (int j=0;j<4;j++)
        acc[i][j] = mfma_bf16(a[i], b[j], acc[i][j]);
  }
  if (z == 2) {
    // write vT [bh][d][s], 4 consecutive s packed per 8B store
    #pragma unroll
    for (int i=0;i<4;i++){
      int mrow = m0 + wr + i*16 + lg*4;
      int b_ = mrow >> 11, s = mrow & 2047;
      #pragma unroll
      for (int j=0;j<4;j++){
        int n = n0 + wc + j*16 + l15;
        float bs = bias[n];
        int h = n >> 6, d = n & 63;
        unsigned int lo = pkbf(acc[i][j][0]+bs, acc[i][j][1]+bs);
        unsigned int hi = pkbf(acc[i][j][2]+bs, acc[i][j][3]+bs);
        unsigned long long v8 = (unsigned long long)lo | ((unsigned long long)hi << 32);
        *reinterpret_cast<unsigned long long*>(
            vto + (((b_*NHEADS + h)*HDIM + d)*SEQL + s)) = v8;
      }
    }
  } else {
    unsigned short* outp = (z==0) ? qo : ko;
    #pragma unroll
    for (int i=0;i<4;i++){
      int mrow = m0 + wr + i*16 + lg*4;
      #pragma unroll
      for (int j=0;j<4;j++){
        int n = n0 + wc + j*16 + l15;
        float bs = bias[n] * bscale;
        int h = n >> 6, d = n & 63;
        #pragma unroll
        for (int r=0;r<4;r++){
          int m = mrow + r;
          int b_ = m >> 11, s = m & 2047;
          outp[(((b_*NHEADS + h)*SEQL) + s)*HDIM + d] = f2bf(acc[i][j][r] + bs);
        }
      }
    }
  }
}

// ---- flash attention: 4 waves, 32 q-rows/wave, KV 64-blocks LDS double-buffered ----
// S^T = mfma(K, Q): lane holds 16 scores of its own q-row (q = lane&15 [+16]).
// O^T = mfma(vT, P): rescale factor lane-uniform. P relayout via swizzled LDS.
// K/V LDS phys layout: linear dest for global_load_lds; source pre-swizzled so
// logical(row, col16) lives at phys col16 ^ (row&7); reads XOR the same way.
__global__ __launch_bounds__(256) void flash(
    const unsigned short* __restrict__ q,   // [bh][s][d], pre-scaled by QSCALE
    const unsigned short* __restrict__ k,   // [bh][s][d]
    const unsigned short* __restrict__ vT,  // [bh][d][s]
    unsigned short* __restrict__ ctx){      // [b][s][HID] bf16
  __shared__ unsigned short Ks[2][4096];    // [64 keys][64 d] bf16, swizzled
  __shared__ unsigned short Vs[2][4096];    // [64 d][64 s] bf16, swizzled
  __shared__ unsigned short Ps[4][2048];    // per-wave [32 q][64 k] bf16, swizzled
  const int bh = blockIdx.y;
  const int b_ = bh >> 4, h = bh & 15;
  const int tid = threadIdx.x;
  const int w = tid >> 6, lane = tid & 63;
  const int l15 = lane & 15, lg = lane >> 4;
  const int q0 = blockIdx.x*128 + w*32;
  const unsigned short* qb = q + (bh*SEQL + q0)*HDIM;
  const unsigned short* kp = k + bh*SEQL*HDIM;
  const unsigned short* vp = vT + bh*HDIM*SEQL;
  char* pw = (char*)Ps[w];
  const int swz = (l15 & 7) << 4;

  // staging geometry: wave w stages rows [w*16, w*16+16) of each 64x64 tile
  const int sr = w*16 + (lane >> 3);            // row for chunk j=0
  const int scol = ((lane & 7) ^ (sr & 7)) * 8; // pre-swizzled source col (elems)
  const int ldst = w*2048;                      // byte offset of chunk j=0 dest

  // Q fragments: [qg][ks]
  u32x4 qf[2][2];
  #pragma unroll
  for (int qg=0; qg<2; qg++)
    #pragma unroll
    for (int ks=0; ks<2; ks++)
      qf[qg][ks] = ld16(&qb[(qg*16 + l15)*HDIM + ks*32 + lg*8]);

  float mr[2] = {-1e30f, -1e30f}, ls[2] = {0.f, 0.f};
  f4_t oacc[4][2];
  f4_t z4 = {0.f,0.f,0.f,0.f};
  #pragma unroll
  for (int dt=0;dt<4;dt++)
    #pragma unroll
    for (int qg=0;qg<2;qg++) oacc[dt][qg] = z4;

  auto stage = [&](int buf, int kb){
    const unsigned short* gk = kp + (kb + sr)*HDIM + scol;
    gload16(gk,           (char*)Ks[buf] + ldst);
    gload16(gk + 8*HDIM,  (char*)Ks[buf] + ldst + 1024);
    const unsigned short* gv = vp + sr*SEQL + kb + scol;
    gload16(gv,           (char*)Vs[buf] + ldst);
    gload16(gv + 8*SEQL,  (char*)Vs[buf] + ldst + 1024);
  };

  int cur = 0;
  stage(0, 0);
  __syncthreads();

  for (int kb = 0; kb < SEQL; kb += 64) {
    if (kb + 64 < SEQL) stage(cur^1, kb + 64);
    const char* kbase = (const char*)Ks[cur];
    const char* vbase = (const char*)Vs[cur];

    f4_t sacc[4][2];
    __builtin_amdgcn_s_setprio(1);
    #pragma unroll
    for (int t=0;t<4;t++){
      u32x4 k0 = *reinterpret_cast<const u32x4*>(kbase + (t*16+l15)*128 + ((lg*16) ^ swz));
      u32x4 k1 = *reinterpret_cast<const u32x4*>(kbase + (t*16+l15)*128 + ((64 + lg*16) ^ swz));
      #pragma unroll
      for (int qg=0;qg<2;qg++){
        f4_t s = mfma_bf16(k0, qf[qg][0], z4);
        sacc[t][qg] = mfma_bf16(k1, qf[qg][1], s);
      }
    }
    __builtin_amdgcn_s_setprio(0);

    float scl[2];
    #pragma unroll
    for (int qg=0;qg<2;qg++){
      float vm = sacc[0][qg][0];
      #pragma unroll
      for (int t=0;t<4;t++)
        #pragma unroll
        for (int r=0;r<4;r++) vm = fmaxf(vm, sacc[t][qg][r]);
      vm = fmaxf(vm, __shfl_xor(vm, 16));
      vm = fmaxf(vm, __shfl_xor(vm, 32));
      float mnew = fmaxf(mr[qg], vm);
      scl[qg] = exp2f(mr[qg] - mnew);
      mr[qg] = mnew;
      float ps = 0.f;
      #pragma unroll
      for (int t=0;t<4;t++)
        #pragma unroll
        for (int r=0;r<4;r++){
          float p = exp2f(sacc[t][qg][r] - mnew);
          sacc[t][qg][r] = p;
          ps += p;
        }
      ps += __shfl_xor(ps, 16);
      ps += __shfl_xor(ps, 32);
      ls[qg] = ls[qg]*scl[qg] + ps;
      // pack P rows into swizzled per-wave LDS
      int rowb = (qg*16 + l15)*128;
      #pragma unroll
      for (int t=0;t<4;t++){
        unsigned int lo = pkbf(sacc[t][qg][0], sacc[t][qg][1]);
        unsigned int hi = pkbf(sacc[t][qg][2], sacc[t][qg][3]);
        unsigned long long v8 = (unsigned long long)lo | ((unsigned long long)hi << 32);
        *reinterpret_cast<unsigned long long*>(pw + rowb + ((t*32 + lg*8) ^ swz)) = v8;
      }
    }
    #pragma unroll
    for (int dt=0;dt<4;dt++)
      #pragma unroll
      for (int qg=0;qg<2;qg++) oacc[dt][qg] *= scl[qg];

    u32x4 pf[2][2];
    #pragma unroll
    for (int qg=0;qg<2;qg++)
      #pragma unroll
      for (int ks=0;ks<2;ks++)
        pf[qg][ks] = *reinterpret_cast<const u32x4*>(
            pw + (qg*16 + l15)*128 + ((ks*64 + lg*16) ^ swz));

    __builtin_amdgcn_s_setprio(1);
    #pragma unroll
    for (int dt=0;dt<4;dt++){
      u32x4 v0 = *reinterpret_cast<const u32x4*>(vbase + (dt*16+l15)*128 + ((lg*16) ^ swz));
      u32x4 v1 = *reinterpret_cast<const u32x4*>(vbase + (dt*16+l15)*128 + ((64 + lg*16) ^ swz));
      #pragma unroll
      for (int qg=0;qg<2;qg++){
        f4_t o = mfma_bf16(v0, pf[qg][0], oacc[dt][qg]);
        oacc[dt][qg] = mfma_bf16(v1, pf[qg][1], o);
      }
    }
    __builtin_amdgcn_s_setprio(0);
    __syncthreads();
    cur ^= 1;
  }

  #pragma unroll
  for (int qg=0;qg<2;qg++){
    float inv = 1.0f / ls[qg];
    int orow = b_*SEQL + q0 + qg*16 + l15;
    unsigned short* cb = ctx + orow*HID + h*HDIM;
    #pragma unroll
    for (int dt=0;dt<4;dt++){
      unsigned int lo = pkbf(oacc[dt][qg][0]*inv, oacc[dt][qg][1]*inv);
      unsigned int hi = pkbf(oacc[dt][qg][2]*inv, oacc[dt][qg][3]*inv);
      unsigned long long v8 = (unsigned long long)lo | ((unsigned long long)hi << 32);
      *reinterpret_cast<unsigned long long*>(cb + dt*16 + lg*4) = v8;
    }
  }
}

// ---- out GEMM: out = ctx[4096,1024] * woT[n,k]^T + bo (fp32 out) ----
__global__ __launch_bounds__(256) void out_gemm(
    const unsigned short* __restrict__ cb,
    const unsigned short* __restrict__ woT,
    const float* __restrict__ bo,
    float* __restrict__ out){
  __shared__ unsigned short As[128*32];
  __shared__ unsigned short Bs[128*32];
  const int m0 = blockIdx.x * 128;
  const int n0 = blockIdx.y * 128;
  const int tid = threadIdx.x;
  const int lane = tid & 63, w = tid >> 6;
  const int l15 = lane & 15, lg = lane >> 4;
  const int wr = (w >> 1) * 64, wc = (w & 1) * 64;
  const int srow = w*16 + (lane >> 2);
  const int skc  = (lane & 3) * 8;

  f4_t acc[4][4];
  f4_t z4 = {0.f,0.f,0.f,0.f};
  #pragma unroll
  for (int i=0;i<4;i++)
    #pragma unroll
    for (int j=0;j<4;j++) acc[i][j] = z4;

  for (int kt = 0; kt < HID; kt += 32) {
    __syncthreads();
    #pragma unroll
    for (int c = 0; c < 2; c++) {
      int row = c*64 + srow;
      gload16(&cb[(m0+row)*HID + kt + skc],  (char*)As + c*4096 + w*1024);
      gload16(&woT[(n0+row)*HID + kt + skc], (char*)Bs + c*4096 + w*1024);
    }
    __syncthreads();
    u32x4 a[4], b[4];
    #pragma unroll
    for (int i=0;i<4;i++) a[i] = ld16(&As[(wr + i*16 + l15)*32 + lg*8]);
    #pragma unroll
    for (int j=0;j<4;j++) b[j] = ld16(&Bs[(wc + j*16 + l15)*32 + lg*8]);
    #pragma unroll
    for (int i=0;i<4;i++)
      #pragma unroll
      for (int j=0;j<4;j++)
        acc[i][j] = mfma_bf16(a[i], b[j], acc[i][j]);
  }
  #pragma unroll
  for (int i=0;i<4;i++){
    int mrow = m0 + wr + i*16 + lg*4;
    #pragma unroll
    for (int j=0;j<4;j++){
      int n = n0 + wc + j*16 + l15;
      float bs = bo[n];
      #pragma unroll
      for (int r=0;r<4;r++)
        out[(mrow + r)*HID + n] = acc[i][j][r] + bs;
    }
  }
}

extern "C" void kernel_launch(void* const* d_in, const int* in_sizes, int n_in,
                              void* d_out, int out_size, void* d_ws, size_t ws_size,
                              hipStream_t stream){
  const float* x  = (const float*)d_in[0];
  const float* Wq = (const float*)d_in[1];
  const float* bq = (const float*)d_in[2];
  const float* Wk = (const float*)d_in[3];
  const float* bk = (const float*)d_in[4];
  const float* Wv = (const float*)d_in[5];
  const float* bv = (const float*)d_in[6];
  const float* Wo = (const float*)d_in[7];
  const float* bo = (const float*)d_in[8];
  float* out = (float*)d_out;

  char* ws = (char*)d_ws;
  size_t off = 0;
  auto alloc = [&](size_t bytes) -> void* {
    void* p = ws + off;
    off += (bytes + 255) & ~(size_t)255;
    return p;
  };
  unsigned short* xb   = (unsigned short*)alloc((size_t)MT*HID*2);
  unsigned short* wqT  = (unsigned short*)alloc((size_t)HID*HID*2);
  unsigned short* wkT  = (unsigned short*)alloc((size_t)HID*HID*2);
  unsigned short* wvT  = (unsigned short*)alloc((size_t)HID*HID*2);
  unsigned short* woT  = (unsigned short*)alloc((size_t)HID*HID*2);
  unsigned short* q_ws = (unsigned short*)alloc((size_t)MT*HID*2);
  unsigned short* k_ws = (unsigned short*)alloc((size_t)MT*HID*2);
  unsigned short* vT_ws= (unsigned short*)alloc((size_t)MT*HID*2);
  unsigned short* c_ws = (unsigned short*)alloc((size_t)MT*HID*2);

  prep_w<<<dim3(32,32,4), dim3(32,8), 0, stream>>>(Wq,Wk,Wv,Wo, wqT,wkT,wvT,woT);
  xcast<<<dim3(2048), dim3(256), 0, stream>>>(x, xb);
  qkv_gemm<<<dim3(32,8,3), dim3(256), 0, stream>>>(xb, wqT,wkT,wvT, bq,bk,bv,
                                                   q_ws, k_ws, vT_ws);
  flash<<<dim3(16,32), dim3(256), 0, stream>>>(q_ws, k_ws, vT_ws, c_ws);
  out_gemm<<<dim3(32,8), dim3(256), 0, stream>>>(c_ws, woT, bo, out);
}

// Round 4
// 163.361 us; speedup vs baseline: 1.9689x; 1.0886x over previous
//
#include <hip/hip_runtime.h>

#define NHEADS 16
#define HDIM   64
#define SEQL   2048
#define HID    1024
#define NB     2
#define MT     4096   // NB*SEQL

// softmax scale folded into Wq/bq: 1/sqrt(64) * log2(e)
#define QSCALE 0.18033688011112042f
// defer-max threshold (log2 domain)
#define RESCALE_THR 6.0f

typedef float        f4_t   __attribute__((ext_vector_type(4)));
typedef unsigned int u32x4  __attribute__((ext_vector_type(4)));
typedef __bf16       bf16x8 __attribute__((ext_vector_type(8)));

typedef const __attribute__((address_space(1))) unsigned int* gas_ptr;
typedef __attribute__((address_space(3))) unsigned int*       las_ptr;

__device__ __forceinline__ void gload16(const void* g, void* l){
  // dest is wave-uniform base; HW writes lane i at base + i*16
  __builtin_amdgcn_global_load_lds((gas_ptr)g, (las_ptr)l, 16, 0, 0);
}
__device__ __forceinline__ unsigned int pkbf(float a, float b){
  unsigned short lo = __builtin_bit_cast(unsigned short, (__bf16)a);
  unsigned short hi = __builtin_bit_cast(unsigned short, (__bf16)b);
  return (unsigned)lo | ((unsigned)hi << 16);
}
__device__ __forceinline__ unsigned short f2bf(float f){
  return __builtin_bit_cast(unsigned short, (__bf16)f);
}
__device__ __forceinline__ u32x4 ld16(const unsigned short* p){
  return *reinterpret_cast<const u32x4*>(p);
}
__device__ __forceinline__ f4_t mfma_bf16(u32x4 a, u32x4 b, f4_t c){
  return __builtin_amdgcn_mfma_f32_16x16x32_bf16(
      __builtin_bit_cast(bf16x8, a), __builtin_bit_cast(bf16x8, b), c, 0, 0, 0);
}

// ---- x fp32 -> bf16 (ushort), 8 elems/thread ----
__global__ __launch_bounds__(256) void xcast(const float* __restrict__ x,
                                             unsigned short* __restrict__ xb){
  int gid = blockIdx.x * 256 + threadIdx.x;
  float4 a = reinterpret_cast<const float4*>(x)[gid * 2];
  float4 b = reinterpret_cast<const float4*>(x)[gid * 2 + 1];
  u32x4 o;
  o[0] = pkbf(a.x, a.y);
  o[1] = pkbf(a.z, a.w);
  o[2] = pkbf(b.x, b.y);
  o[3] = pkbf(b.z, b.w);
  *reinterpret_cast<u32x4*>(&xb[gid * 8]) = o;
}

// ---- W [K,N] fp32 -> W^T [N,K] bf16, 32x32 tiles; Wq scaled by QSCALE ----
__global__ void prep_w(const float* __restrict__ Wq, const float* __restrict__ Wk,
                       const float* __restrict__ Wv, const float* __restrict__ Wo,
                       unsigned short* __restrict__ wqT, unsigned short* __restrict__ wkT,
                       unsigned short* __restrict__ wvT, unsigned short* __restrict__ woT){
  __shared__ float t[32][33];
  int z = blockIdx.z;
  const float* W = (z==0)?Wq:(z==1)?Wk:(z==2)?Wv:Wo;
  unsigned short* WT = (z==0)?wqT:(z==1)?wkT:(z==2)?wvT:woT;
  float sc = (z==0) ? QSCALE : 1.0f;
  int k0 = blockIdx.x*32, n0 = blockIdx.y*32;
  int tx = threadIdx.x, ty = threadIdx.y;
  #pragma unroll
  for (int ii=0; ii<4; ii++)
    t[ty+ii*8][tx] = W[(k0+ty+ii*8)*HID + n0+tx];
  __syncthreads();
  #pragma unroll
  for (int ii=0; ii<4; ii++)
    WT[(n0+ty+ii*8)*HID + k0+tx] = f2bf(t[tx][ty+ii*8] * sc);
}

// ---- QKV GEMM: C = xb[4096,1024] * WT[n,k]^T + bias ----
// z==0 -> q [bh,s,d] (pre-scaled), z==1 -> k [bh,s,d], z==2 -> vT [bh,d,s]
__global__ __launch_bounds__(256) void qkv_gemm(
    const unsigned short* __restrict__ xb,
    const unsigned short* __restrict__ wqT, const unsigned short* __restrict__ wkT,
    const unsigned short* __restrict__ wvT,
    const float* __restrict__ bq, const float* __restrict__ bk, const float* __restrict__ bv,
    unsigned short* __restrict__ qo, unsigned short* __restrict__ ko,
    unsigned short* __restrict__ vto){
  __shared__ unsigned short As[128*32];
  __shared__ unsigned short Bs[128*32];
  const int z = blockIdx.z;
  const unsigned short* wT = (z==0)?wqT:(z==1)?wkT:wvT;
  const float* bias = (z==0)?bq:(z==1)?bk:bv;
  const float bscale = (z==0) ? QSCALE : 1.0f;
  const int m0 = blockIdx.x * 128;
  const int n0 = blockIdx.y * 128;
  const int tid = threadIdx.x;
  const int lane = tid & 63, w = tid >> 6;
  const int l15 = lane & 15, lg = lane >> 4;
  const int wr = (w >> 1) * 64, wc = (w & 1) * 64;
  const int srow = w*16 + (lane >> 2);     // staging row within 64-row chunk
  const int skc  = (lane & 3) * 8;         // staging k-chunk

  f4_t acc[4][4];
  f4_t z4 = {0.f, 0.f, 0.f, 0.f};
  #pragma unroll
  for (int i=0;i<4;i++)
    #pragma unroll
    for (int j=0;j<4;j++) acc[i][j] = z4;

  for (int kt = 0; kt < HID; kt += 32) {
    __syncthreads();
    #pragma unroll
    for (int c = 0; c < 2; c++) {
      int row = c*64 + srow;
      gload16(&xb[(m0+row)*HID + kt + skc], (char*)As + c*4096 + w*1024);
      gload16(&wT[(n0+row)*HID + kt + skc], (char*)Bs + c*4096 + w*1024);
    }
    __syncthreads();
    u32x4 a[4], b[4];
    #pragma unroll
    for (int i=0;i<4;i++) a[i] = ld16(&As[(wr + i*16 + l15)*32 + lg*8]);
    #pragma unroll
    for (int j=0;j<4;j++) b[j] = ld16(&Bs[(wc + j*16 + l15)*32 + lg*8]);
    #pragma unroll
    for (int i=0;i<4;i++)
      #pragma unroll
      for (int j=0;j<4;j++)
        acc[i][j] = mfma_bf16(a[i], b[j], acc[i][j]);
  }
  if (z == 2) {
    // write vT [bh][d][s], 4 consecutive s packed per 8B store
    #pragma unroll
    for (int i=0;i<4;i++){
      int mrow = m0 + wr + i*16 + lg*4;
      int b_ = mrow >> 11, s = mrow & 2047;
      #pragma unroll
      for (int j=0;j<4;j++){
        int n = n0 + wc + j*16 + l15;
        float bs = bias[n];
        int h = n >> 6, d = n & 63;
        unsigned int lo = pkbf(acc[i][j][0]+bs, acc[i][j][1]+bs);
        unsigned int hi = pkbf(acc[i][j][2]+bs, acc[i][j][3]+bs);
        unsigned long long v8 = (unsigned long long)lo | ((unsigned long long)hi << 32);
        *reinterpret_cast<unsigned long long*>(
            vto + (((b_*NHEADS + h)*HDIM + d)*SEQL + s)) = v8;
      }
    }
  } else {
    unsigned short* outp = (z==0) ? qo : ko;
    #pragma unroll
    for (int i=0;i<4;i++){
      int mrow = m0 + wr + i*16 + lg*4;
      #pragma unroll
      for (int j=0;j<4;j++){
        int n = n0 + wc + j*16 + l15;
        float bs = bias[n] * bscale;
        int h = n >> 6, d = n & 63;
        #pragma unroll
        for (int r=0;r<4;r++){
          int m = mrow + r;
          int b_ = m >> 11, s = m & 2047;
          outp[(((b_*NHEADS + h)*SEQL) + s)*HDIM + d] = f2bf(acc[i][j][r] + bs);
        }
      }
    }
  }
}

// ---- flash attention: 8 waves, 16 q-rows/wave, KV 64-blocks LDS double-buffered ----
// S^T = mfma(K, Q): lane holds 16 scores of its own q-row (q = lane&15).
// O^T = mfma(vT, P): rescale factor lane-uniform. P relayout via swizzled LDS.
// Defer-max: skip rescale when per-tile max growth <= RESCALE_THR (log2 units).
__global__ __launch_bounds__(512) void flash(
    const unsigned short* __restrict__ q,   // [bh][s][d], pre-scaled by QSCALE
    const unsigned short* __restrict__ k,   // [bh][s][d]
    const unsigned short* __restrict__ vT,  // [bh][d][s]
    unsigned short* __restrict__ ctx){      // [b][s][HID] bf16
  __shared__ unsigned short Ks[2][4096];    // [64 keys][64 d] bf16, swizzled
  __shared__ unsigned short Vs[2][4096];    // [64 d][64 s] bf16, swizzled
  __shared__ unsigned short Ps[8][1024];    // per-wave [16 q][64 k] bf16, swizzled
  const int bh = blockIdx.y;
  const int b_ = bh >> 4, h = bh & 15;
  const int tid = threadIdx.x;
  const int w = tid >> 6, lane = tid & 63;
  const int l15 = lane & 15, lg = lane >> 4;
  const int q0 = blockIdx.x*128 + w*16;
  const unsigned short* qb = q + (bh*SEQL + q0)*HDIM;
  const unsigned short* kp = k + bh*SEQL*HDIM;
  const unsigned short* vp = vT + bh*HDIM*SEQL;
  char* pw = (char*)Ps[w];
  const int swz = (l15 & 7) << 4;

  // staging geometry: wave w stages rows [w*8, w*8+8) of each 64x64 tile
  const int sr = w*8 + (lane >> 3);             // staging row
  const int scol = ((lane & 7) ^ (sr & 7)) * 8; // pre-swizzled source col (elems)
  const int ldst = w*1024;                      // byte offset of staging dest

  u32x4 qf[2];
  #pragma unroll
  for (int ks=0; ks<2; ks++)
    qf[ks] = ld16(&qb[l15*HDIM + ks*32 + lg*8]);

  float mr = -1e30f, ls = 0.f;
  f4_t oacc[4];
  f4_t z4 = {0.f,0.f,0.f,0.f};
  #pragma unroll
  for (int dt=0;dt<4;dt++) oacc[dt] = z4;

  auto stage = [&](int buf, int kb){
    gload16(kp + (kb + sr)*HDIM + scol, (char*)Ks[buf] + ldst);
    gload16(vp + sr*SEQL + kb + scol,   (char*)Vs[buf] + ldst);
  };

  int cur = 0;
  stage(0, 0);
  __syncthreads();

  for (int kb = 0; kb < SEQL; kb += 64) {
    if (kb + 64 < SEQL) stage(cur^1, kb + 64);
    const char* kbase = (const char*)Ks[cur];
    const char* vbase = (const char*)Vs[cur];

    f4_t sacc[4];
    __builtin_amdgcn_s_setprio(1);
    #pragma unroll
    for (int t=0;t<4;t++){
      u32x4 k0 = *reinterpret_cast<const u32x4*>(kbase + (t*16+l15)*128 + ((lg*16) ^ swz));
      u32x4 k1 = *reinterpret_cast<const u32x4*>(kbase + (t*16+l15)*128 + ((64 + lg*16) ^ swz));
      f4_t s = mfma_bf16(k0, qf[0], z4);
      sacc[t] = mfma_bf16(k1, qf[1], s);
    }
    __builtin_amdgcn_s_setprio(0);

    float vm = sacc[0][0];
    #pragma unroll
    for (int t=0;t<4;t++)
      #pragma unroll
      for (int r=0;r<4;r++) vm = fmaxf(vm, sacc[t][r]);
    vm = fmaxf(vm, __shfl_xor(vm, 16));
    vm = fmaxf(vm, __shfl_xor(vm, 32));
    // defer-max: only rescale when the new tile max meaningfully exceeds mr
    if (!__all(vm - mr <= RESCALE_THR)) {
      float mnew = fmaxf(mr, vm);
      float scl = exp2f(mr - mnew);
      mr = mnew;
      ls *= scl;
      #pragma unroll
      for (int dt=0;dt<4;dt++) oacc[dt] *= scl;
    }
    float ps = 0.f;
    #pragma unroll
    for (int t=0;t<4;t++)
      #pragma unroll
      for (int r=0;r<4;r++){
        float p = exp2f(sacc[t][r] - mr);
        sacc[t][r] = p;
        ps += p;
      }
    ps += __shfl_xor(ps, 16);
    ps += __shfl_xor(ps, 32);
    ls += ps;
    // pack P rows into swizzled per-wave LDS
    {
      int rowb = l15*128;
      #pragma unroll
      for (int t=0;t<4;t++){
        unsigned int lo = pkbf(sacc[t][0], sacc[t][1]);
        unsigned int hi = pkbf(sacc[t][2], sacc[t][3]);
        unsigned long long v8 = (unsigned long long)lo | ((unsigned long long)hi << 32);
        *reinterpret_cast<unsigned long long*>(pw + rowb + ((t*32 + lg*8) ^ swz)) = v8;
      }
    }
    u32x4 pf[2];
    #pragma unroll
    for (int ks=0;ks<2;ks++)
      pf[ks] = *reinterpret_cast<const u32x4*>(
          pw + l15*128 + ((ks*64 + lg*16) ^ swz));

    __builtin_amdgcn_s_setprio(1);
    #pragma unroll
    for (int dt=0;dt<4;dt++){
      u32x4 v0 = *reinterpret_cast<const u32x4*>(vbase + (dt*16+l15)*128 + ((lg*16) ^ swz));
      u32x4 v1 = *reinterpret_cast<const u32x4*>(vbase + (dt*16+l15)*128 + ((64 + lg*16) ^ swz));
      f4_t o = mfma_bf16(v0, pf[0], oacc[dt]);
      oacc[dt] = mfma_bf16(v1, pf[1], o);
    }
    __builtin_amdgcn_s_setprio(0);
    __syncthreads();
    cur ^= 1;
  }

  float inv = 1.0f / ls;
  int orow = b_*SEQL + q0 + l15;
  unsigned short* cb = ctx + orow*HID + h*HDIM;
  #pragma unroll
  for (int dt=0;dt<4;dt++){
    unsigned int lo = pkbf(oacc[dt][0]*inv, oacc[dt][1]*inv);
    unsigned int hi = pkbf(oacc[dt][2]*inv, oacc[dt][3]*inv);
    unsigned long long v8 = (unsigned long long)lo | ((unsigned long long)hi << 32);
    *reinterpret_cast<unsigned long long*>(cb + dt*16 + lg*4) = v8;
  }
}

// ---- out GEMM: out = ctx[4096,1024] * woT[n,k]^T + bo (fp32 out) ----
__global__ __launch_bounds__(256) void out_gemm(
    const unsigned short* __restrict__ cb,
    const unsigned short* __restrict__ woT,
    const float* __restrict__ bo,
    float* __restrict__ out){
  __shared__ unsigned short As[128*32];
  __shared__ unsigned short Bs[128*32];
  const int m0 = blockIdx.x * 128;
  const int n0 = blockIdx.y * 128;
  const int tid = threadIdx.x;
  const int lane = tid & 63, w = tid >> 6;
  const int l15 = lane & 15, lg = lane >> 4;
  const int wr = (w >> 1) * 64, wc = (w & 1) * 64;
  const int srow = w*16 + (lane >> 2);
  const int skc  = (lane & 3) * 8;

  f4_t acc[4][4];
  f4_t z4 = {0.f,0.f,0.f,0.f};
  #pragma unroll
  for (int i=0;i<4;i++)
    #pragma unroll
    for (int j=0;j<4;j++) acc[i][j] = z4;

  for (int kt = 0; kt < HID; kt += 32) {
    __syncthreads();
    #pragma unroll
    for (int c = 0; c < 2; c++) {
      int row = c*64 + srow;
      gload16(&cb[(m0+row)*HID + kt + skc],  (char*)As + c*4096 + w*1024);
      gload16(&woT[(n0+row)*HID + kt + skc], (char*)Bs + c*4096 + w*1024);
    }
    __syncthreads();
    u32x4 a[4], b[4];
    #pragma unroll
    for (int i=0;i<4;i++) a[i] = ld16(&As[(wr + i*16 + l15)*32 + lg*8]);
    #pragma unroll
    for (int j=0;j<4;j++) b[j] = ld16(&Bs[(wc + j*16 + l15)*32 + lg*8]);
    #pragma unroll
    for (int i=0;i<4;i++)
      #pragma unroll
      for (int j=0;j<4;j++)
        acc[i][j] = mfma_bf16(a[i], b[j], acc[i][j]);
  }
  #pragma unroll
  for (int i=0;i<4;i++){
    int mrow = m0 + wr + i*16 + lg*4;
    #pragma unroll
    for (int j=0;j<4;j++){
      int n = n0 + wc + j*16 + l15;
      float bs = bo[n];
      #pragma unroll
      for (int r=0;r<4;r++)
        out[(mrow + r)*HID + n] = acc[i][j][r] + bs;
    }
  }
}

extern "C" void kernel_launch(void* const* d_in, const int* in_sizes, int n_in,
                              void* d_out, int out_size, void* d_ws, size_t ws_size,
                              hipStream_t stream){
  const float* x  = (const float*)d_in[0];
  const float* Wq = (const float*)d_in[1];
  const float* bq = (const float*)d_in[2];
  const float* Wk = (const float*)d_in[3];
  const float* bk = (const float*)d_in[4];
  const float* Wv = (const float*)d_in[5];
  const float* bv = (const float*)d_in[6];
  const float* Wo = (const float*)d_in[7];
  const float* bo = (const float*)d_in[8];
  float* out = (float*)d_out;

  char* ws = (char*)d_ws;
  size_t off = 0;
  auto alloc = [&](size_t bytes) -> void* {
    void* p = ws + off;
    off += (bytes + 255) & ~(size_t)255;
    return p;
  };
  unsigned short* xb   = (unsigned short*)alloc((size_t)MT*HID*2);
  unsigned short* wqT  = (unsigned short*)alloc((size_t)HID*HID*2);
  unsigned short* wkT  = (unsigned short*)alloc((size_t)HID*HID*2);
  unsigned short* wvT  = (unsigned short*)alloc((size_t)HID*HID*2);
  unsigned short* woT  = (unsigned short*)alloc((size_t)HID*HID*2);
  unsigned short* q_ws = (unsigned short*)alloc((size_t)MT*HID*2);
  unsigned short* k_ws = (unsigned short*)alloc((size_t)MT*HID*2);
  unsigned short* vT_ws= (unsigned short*)alloc((size_t)MT*HID*2);
  unsigned short* c_ws = (unsigned short*)alloc((size_t)MT*HID*2);

  prep_w<<<dim3(32,32,4), dim3(32,8), 0, stream>>>(Wq,Wk,Wv,Wo, wqT,wkT,wvT,woT);
  xcast<<<dim3(2048), dim3(256), 0, stream>>>(x, xb);
  qkv_gemm<<<dim3(32,8,3), dim3(256), 0, stream>>>(xb, wqT,wkT,wvT, bq,bk,bv,
                                                   q_ws, k_ws, vT_ws);
  flash<<<dim3(16,32), dim3(512), 0, stream>>>(q_ws, k_ws, vT_ws, c_ws);
  out_gemm<<<dim3(32,8), dim3(256), 0, stream>>>(c_ws, woT, bo, out);
}